// Round 15
// baseline (706.921 us; speedup 1.0000x reference)
//
#include <hip/hip_runtime.h>
#include <hip/hip_bf16.h>
#include <stdint.h>

typedef __bf16 bf16;
typedef __bf16 bfrag __attribute__((ext_vector_type(8)));
typedef short s16x8 __attribute__((ext_vector_type(8)));
typedef float f32x4 __attribute__((ext_vector_type(4)));
typedef float f32x16 __attribute__((ext_vector_type(16)));
typedef uint32_t u32x4 __attribute__((ext_vector_type(4)));

#define DEV __device__ __forceinline__

DEV bfrag ldg16(const bf16* p){ return *(const bfrag*)p; }

struct U64x2 { uint64_t a, b; };
DEV bfrag ld2x8(const bf16* p){
  U64x2 t; t.a = *(const uint64_t*)p; t.b = *(const uint64_t*)(p+4);
  return __builtin_bit_cast(bfrag, t);
}
// 16B from LDS as 4 dword loads (4B-aligned safe — used with 76B pixel stride)
DEV bfrag ld4x4(const char* p){
  u32x4 t;
  t[0] = *(const uint32_t*)p;
  t[1] = *(const uint32_t*)(p+4);
  t[2] = *(const uint32_t*)(p+8);
  t[3] = *(const uint32_t*)(p+12);
  return __builtin_bit_cast(bfrag, t);
}

DEV f32x4  mfma16(bfrag a, bfrag b, f32x4  c){ return __builtin_amdgcn_mfma_f32_16x16x32_bf16(a,b,c,0,0,0); }
DEV f32x16 mfma32(bfrag a, bfrag b, f32x16 c){ return __builtin_amdgcn_mfma_f32_32x32x16_bf16(a,b,c,0,0,0); }

DEV f32x16 zero16(){
  f32x16 v;
  for(int i=0;i<16;++i) v[i]=0.f;
  return v;
}
DEV f32x4 zero4(){
  f32x4 v;
  for(int i=0;i<4;++i) v[i]=0.f;
  return v;
}

DEV float sigm(float x){ return 1.0f/(1.0f+__expf(-x)); }
DEV float ftanh(float x){ float e = __expf(2.f*x); return 1.f - 2.f/(e+1.f); }

// coherent (L1+L2-bypass) 16B load — reads straight from the IF coherence point
DEV u32x4 ldcg4(const uint32_t* p){
  u32x4 r;
  asm volatile("global_load_dwordx4 %0, %1, off sc0 sc1" : "=v"(r) : "v"(p));
  return r;
}

DEV uint32_t pk2f(float a, float b){
  bf16 x = (bf16)a, y = (bf16)b;
  return (uint32_t)__builtin_bit_cast(uint16_t,x) | ((uint32_t)__builtin_bit_cast(uint16_t,y)<<16);
}

// async global->LDS 16B: per-lane global src, wave-uniform LDS base + lane*16
DEV void gl_lds16(const bf16* g, void* l){
  __builtin_amdgcn_global_load_lds(
      (const __attribute__((address_space(1))) uint32_t*)g,
      (__attribute__((address_space(3))) uint32_t*)l, 16, 0, 0);
}

// ---------------------------------------------------------------- k_prep
__global__ __launch_bounds__(256) void k_prep(
    const float* __restrict__ c1w, const float* __restrict__ c2w,
    const float* __restrict__ c3w, const float* __restrict__ fcw,
    const float* __restrict__ Wih, const float* __restrict__ WhhF,
    const float* __restrict__ bih, const float* __restrict__ bhh,
    const float* __restrict__ aw1, const float* __restrict__ aw2,
    const float* __restrict__ vw1, const float* __restrict__ vw2,
    const float* __restrict__ h0, const float* __restrict__ ab1,
    const float* __restrict__ vb1,
    bf16* w1b, bf16* w2r, bf16* w3r, bf16* fcwr, bf16* Wx, bf16* Whh,
    float* biasL, float* Wr, float* Wa, bf16* headw1, float* headb1,
    bf16* w2cat, uint32_t* hcurT)
{
  long i = (long)blockIdx.x*256 + threadIdx.x;
  if (i < 2048){ int co=(int)(i>>6), k=(int)(i&63);
    w1b[i] = (bf16)(c1w[co*64+k]*(1.f/255.f)); return; } i -= 2048;
  if (i < 32768){ int o=(int)(i>>9), k=(int)(i&511);
    int ky=k>>7, kx=(k>>5)&3, ci=k&31;
    w2r[i] = (bf16)c2w[((o*32+ci)*4+ky)*4+kx]; return; } i -= 32768;
  if (i < 36864){ int o=(int)(i/576), k=(int)(i%576);
    int ky=k/192, rem=k-ky*192, kx=rem>>6, ci=rem&63;
    w3r[i] = (bf16)c3w[((o*64+ci)*3+ky)*3+kx]; return; } i -= 36864;
  if (i < 1605632){ // fcw: source-coalesced read, scattered write
    int o=(int)(i/3136), rem=(int)(i%3136);
    int ci=rem/49, yx=rem-ci*49, y=yx/7, x=yx-y*7;
    fcwr[o*3200 + y*448 + x*64 + ci] = (bf16)fcw[i]; return; } i -= 1605632;
  if (i < 32768){ int o=(int)(i>>6), k=(int)(i&63);
    fcwr[o*3200 + 3136 + k] = (bf16)0.f; return; } i -= 32768;
  if (i < 1048576){ int n=(int)(i>>9), k=(int)(i&511);
    Wx[i] = (bf16)Wih[n*531+k]; return; } i -= 1048576;
  if (i < 1048576){ int n=(int)(i>>9), k=(int)(i&511);
    Whh[i] = (bf16)WhhF[n*512+k]; return; } i -= 1048576;
  if (i < 2048){ biasL[i] = bih[i]+bhh[i]; return; } i -= 2048;
  if (i < 2048){ Wr[i] = Wih[i*531+512]; return; } i -= 2048;
  if (i < 36864){ int j=(int)(i>>11), n=(int)(i&2047);
    Wa[i] = Wih[n*531+513+j]; return; } i -= 36864;
  if (i < 524288){ headw1[i] = (bf16)(i<262144 ? aw1[i] : vw1[i-262144]); return; } i -= 524288;
  if (i < 1024){ headb1[i] = (i<512) ? ab1[i] : vb1[i-512]; return; } i -= 1024;
  if (i < 32768){ int n=(int)(i>>10), k=(int)(i&1023);
    float v = 0.f;
    if (n<18 && k<512) v = aw2[n*512+k];
    else if (n==18 && k>=512) v = vw2[k-512];
    w2cat[i] = (bf16)v; return; } i -= 32768;
  if (i < 32768){
    if (i < 16384){
      int row = (int)(i>>8), wd = (int)(i&255);
      uint32_t pk = pk2f(h0[row*512 + wd*2], h0[row*512 + wd*2 + 1]);
      hcurT[i] = pk & ~0x00010001u;
    } else {
      hcurT[i] = 0x00010000u;
    }
    return;
  }
}

// ---------------------------------------------------------------- conv1+conv2 fused
// 512 threads (8 waves, 4/image), 2 images/block, 60.8KB LDS -> 2 blocks/CU
// (16 waves/CU). conv2 on mfma16: wave q owns col tile q*16, 6 row tiles.
__global__ __launch_bounds__(512,2) void k_conv12(
    const int* __restrict__ o, const bf16* __restrict__ w1b,
    const float* __restrict__ c1b, const bf16* __restrict__ w2r,
    const float* __restrict__ c2b, bf16* __restrict__ act2)
{
  __shared__ bf16 lact[2][15200];    // 2 img x 400 px x 76B (60800 B)
  const int tid = threadIdx.x;
  const int w = tid>>6, l = tid&63;
  const int img = w>>2, q = w&3;     // 4 waves per image
  const long gimg = (long)blockIdx.x*2 + img;
  const int* ip = o + gimg*7056;
  char* lw = (char*)&lact[img][0];
  // ---- conv1 (mfma32, N=32): waves of an image split mt tiles mod 4
  {
    bfrag bw[4];
    #pragma unroll
    for (int ks=0;ks<4;++ks) bw[ks] = ldg16(w1b + (l&31)*64 + ks*16 + 8*(l>>5));
    const float bias = c1b[l&31];
    for (int mt=q; mt<13; mt+=4){
      f32x16 acc = zero16();
      int m0 = mt*32 + (l&31);
      int p  = m0>399 ? 399 : m0;
      int oy = p/20, ox = p - oy*20;
      #pragma unroll
      for (int ks=0;ks<4;++ks){
        int ky = 2*ks + (l>>5);
        const int* qq = ip + (oy*4+ky)*84 + ox*4;
        int4 i0 = *(const int4*)qq;
        int4 i1 = *(const int4*)(qq+4);
        bfrag a;
        a[0]=(bf16)(float)i0.x; a[1]=(bf16)(float)i0.y;
        a[2]=(bf16)(float)i0.z; a[3]=(bf16)(float)i0.w;
        a[4]=(bf16)(float)i1.x; a[5]=(bf16)(float)i1.y;
        a[6]=(bf16)(float)i1.z; a[7]=(bf16)(float)i1.w;
        acc = mfma32(a, bw[ks], acc);
      }
      #pragma unroll
      for (int r2=0;r2<16;++r2){
        int row = (r2&3) + 8*(r2>>2) + 4*(l>>5);
        int m = mt*32 + row;
        if (m < 400){
          float v = acc[r2] + bias; v = v>0.f ? v : 0.f;
          *(bf16*)(lw + m*76 + (l&31)*2) = (bf16)v;
        }
      }
    }
  }
  __syncthreads();
  // ---- conv2 (mfma16): wave q -> out cols [q*16, q*16+16), 6 row tiles of 16
  {
    const int col = q*16 + (l&15);
    bfrag wb[16];
    #pragma unroll
    for (int ks=0;ks<16;++ks) wb[ks] = ldg16(w2r + (long)col*512 + ks*32 + 8*(l>>4));
    // per-lane pixel bases for the 6 row tiles
    int pbase[6];
    #pragma unroll
    for (int rt=0;rt<6;++rt){
      int m = rt*16 + (l&15); int p = m>80 ? 80 : m;
      int oy = p/9, ox = p - oy*9;
      pbase[rt] = ((oy*2)*20 + ox*2)*76 + 16*(l>>4);
    }
    f32x4 acc[6];
    #pragma unroll
    for (int rt=0;rt<6;++rt) acc[rt] = zero4();
    #pragma unroll 4
    for (int ks=0; ks<16; ++ks){
      int ky = ks>>2, kx = ks&3;
      int koff = (ky*20 + kx)*76;
      #pragma unroll
      for (int rt=0;rt<6;++rt){
        bfrag a = ld4x4(lw + pbase[rt] + koff);
        acc[rt] = mfma16(a, wb[ks], acc[rt]);
      }
    }
    const float bias2 = c2b[col];
    #pragma unroll
    for (int rt=0;rt<6;++rt){
      #pragma unroll
      for (int r2=0;r2<4;++r2){
        int m = rt*16 + (l>>4)*4 + r2;
        if (m < 81){
          float v = acc[rt][r2] + bias2; v = v>0.f ? v : 0.f;
          act2[gimg*5184 + m*64 + col] = (bf16)v;
        }
      }
    }
  }
}

// ---------------------------------------------------------------- conv3
__global__ __launch_bounds__(256,2) void k_conv3(
    const bf16* __restrict__ act2, const bf16* __restrict__ w3r,
    const float* __restrict__ c3b, bf16* __restrict__ act3)
{
  const int tid=threadIdx.x, w=tid>>6, l=tid&63;
  const long img = (long)blockIdx.x*4 + w;
  const bf16* A = act2 + img*5184;
  f32x16 acc[2][2];
  #pragma unroll
  for(int a2=0;a2<2;++a2){ acc[a2][0]=zero16(); acc[a2][1]=zero16(); }
  #pragma unroll 4
  for (int ks=0; ks<36; ++ks){
    int k  = ks*16 + 8*(l>>5);
    int ky = k/192, rem = k - ky*192, kx = rem>>6, ci = rem&63;
    bfrag b0 = ldg16(w3r + (l&31)*576 + k);
    bfrag b1 = ldg16(w3r + (32+(l&31))*576 + k);
    #pragma unroll
    for (int mt=0; mt<2; ++mt){
      int m = mt*32 + (l&31); int p = m>48 ? 48 : m;
      int oy = p/7, ox = p - oy*7;
      bfrag a = ldg16(A + ((oy+ky)*9 + (ox+kx))*64 + ci);
      acc[mt][0] = mfma32(a, b0, acc[mt][0]);
      acc[mt][1] = mfma32(a, b1, acc[mt][1]);
    }
  }
  const float bias0 = c3b[l&31], bias1 = c3b[32+(l&31)];
  #pragma unroll
  for (int mt=0; mt<2; ++mt){
    #pragma unroll
    for (int r2=0;r2<16;++r2){
      int row = (r2&3) + 8*(r2>>2) + 4*(l>>5);
      int m = mt*32 + row;
      if (m < 50){
        float v0 = 0.f, v1 = 0.f;
        if (m < 49){
          v0 = acc[mt][0][r2] + bias0; v0 = v0>0.f ? v0 : 0.f;
          v1 = acc[mt][1][r2] + bias1; v1 = v1>0.f ? v1 : 0.f;
        }
        act3[img*3200 + m*64 + (l&31)]      = (bf16)v0;
        act3[img*3200 + m*64 + 32 + (l&31)] = (bf16)v1;
      }
    }
  }
}

// ---------------------------------------------------------------- generic GEMM
template<bool RELU, bool OUTBF16>
__global__ __launch_bounds__(256,4) void k_gemm(
    const bf16* __restrict__ A, long lda,
    const bf16* __restrict__ W, long ldb,
    const float* __restrict__ bias,
    float* __restrict__ outF, bf16* __restrict__ outB, long ldo, int K,
    const float* __restrict__ fixR, const int* __restrict__ fixA,
    const float* __restrict__ fixWr, const float* __restrict__ fixWa)
{
  __shared__ bf16 sA[8192];
  char* sb = (char*)sA;
  const int tid=threadIdx.x, w=tid>>6, l=tid&63;
  const int m0 = blockIdx.x*64, n0 = blockIdx.y*128;
  f32x16 acc[2]; acc[0]=zero16(); acc[1]=zero16();
  const int mt = w&1;
  const int rowa = mt*32 + (l&31);
  for (int kc=0; kc<K; kc+=128){
    __syncthreads();
    #pragma unroll
    for (int j=0;j<4;++j){
      int idx = j*64 + l;
      int row = w*16 + (idx>>4);
      int seg = idx&15;
      const bf16* gp = A + (long)(m0+row)*lda + kc + (((seg*16) ^ ((row&15)<<4))>>1);
      gl_lds16(gp, sb + w*4096 + j*1024);
    }
    asm volatile("s_waitcnt vmcnt(0)" ::: "memory");
    __syncthreads();
    #pragma unroll
    for (int ks=0; ks<8; ++ks){
      bfrag a = *(const bfrag*)(sb + rowa*256 + ((ks*32 + (l>>5)*16) ^ ((rowa&15)<<4)));
      #pragma unroll
      for (int j=0;j<2;++j){
        int nt = (w>>1)*2 + j;
        bfrag b = ldg16(W + (long)(n0 + nt*32 + (l&31))*ldb + kc + ks*16 + 8*(l>>5));
        acc[j] = mfma32(a, b, acc[j]);
      }
    }
  }
  #pragma unroll
  for (int j=0;j<2;++j){
    int nt = (w>>1)*2 + j;
    int gc = n0 + nt*32 + (l&31);
    float bv = bias ? bias[gc] : 0.f;
    float wrv = fixR ? fixWr[gc] : 0.f;
    #pragma unroll
    for (int r2=0;r2<16;++r2){
      int row = (r2&3) + 8*(r2>>2) + 4*(l>>5);
      long gr = m0 + mt*32 + row;
      float v = acc[j][r2] + bv;
      if (fixR) v += fixR[gr]*wrv + fixWa[(long)fixA[gr]*2048 + gc];
      if (RELU) v = v>0.f ? v : 0.f;
      if (OUTBF16) outB[gr*ldo + gc] = (bf16)v;
      else         outF[gr*ldo + gc] = v;
    }
  }
}

// ---------------------------------------------------------------- LSTM recurrence (single 80-step dispatch)
// W_hh pinned in VGPRs; sc1 tag-in-data h exchange; G read as bf16.
__global__ __launch_bounds__(256,1) void k_lstm(
    const bf16* __restrict__ G, const int* __restrict__ done,
    const float* __restrict__ c0, const bf16* __restrict__ Whh,
    uint32_t* __restrict__ hcurT, bf16* __restrict__ hseq,
    float* __restrict__ outH, float* __restrict__ outC)
{
  __shared__ bf16 sh2[8192];         // 16 frags x 64 lanes x 8bf16 (16KB)
  __shared__ float sg[4][16][33];
  __shared__ float sc[16][33];
  __shared__ char  sdone[80][16];
  const int tid=threadIdx.x, w=tid>>6, l=tid&63;
  const int blk=blockIdx.x;
  const int grp=(blk&7)>>1, jj=((blk&1)<<3)|(blk>>3);
  const int bb = grp*16, uu = jj*32;

  for (int p=tid; p<512; p+=256){ int m=p>>5, u=p&31; sc[m][u] = c0[(bb+m)*512 + uu + u]; }
  for (int p=tid; p<1280; p+=256){ int t=p>>4, m=p&15; sdone[t][m] = (char)done[t*64 + bb + m]; }

  // W_hh fragments -> registers, pinned (cannot be rematerialized past the asm)
  bfrag wb0[16], wb1[16];
  {
    const long row0 = (long)w*512 + uu + (l&15);
    #pragma unroll
    for (int ks=0; ks<16; ++ks){
      int k = ks*32 + 8*(l>>4);
      wb0[ks] = ldg16(Whh + row0*512 + k);
      wb1[ks] = ldg16(Whh + (row0+16)*512 + k);
      asm volatile("" : "+v"(wb0[ks]), "+v"(wb1[ks]));
    }
  }

  char* shb = (char*)sh2;
  const int loff = l*16;
  const int srow  = tid>>4;
  const int sci   = tid&15;

  __syncthreads();

  for (int t=0; t<80; ++t){
    // (a) G loads for this step — independent of h, overlap the poll
    float gv0[4], gv1[4];
    {
      const bf16* Gt = G + ((long)t*64 + bb)*2048 + w*512 + uu;
      #pragma unroll
      for (int r2=0;r2<4;++r2){
        int m2 = (l>>4)*4 + r2;
        gv0[r2] = (float)Gt[(long)m2*2048 + (l&15)];
        gv1[r2] = (float)Gt[(long)m2*2048 + 16 + (l&15)];
      }
    }
    __builtin_amdgcn_sched_barrier(0);
    // (b) poll tagged bf16-pair h words for step t
    {
      const uint32_t* hb = hcurT + (size_t)(t&1)*16384 + (size_t)(bb+srow)*256 + sci*16;
      u32x4 hv[4];
      const uint32_t expPat = ((uint32_t)(t&1)) | (((uint32_t)((t>>1)&1))<<16);
      for (;;){
        #pragma unroll
        for (int j2=0;j2<4;++j2) hv[j2] = ldcg4(hb + j2*4);
        asm volatile("s_waitcnt vmcnt(0)" ::: "memory");
        bool ok = true;
        #pragma unroll
        for (int j2=0;j2<4;++j2){
          ok &= ((hv[j2][0]&0x00010001u)==expPat) & ((hv[j2][1]&0x00010001u)==expPat)
              & ((hv[j2][2]&0x00010001u)==expPat) & ((hv[j2][3]&0x00010001u)==expPat);
        }
        if (__all(ok)) break;
        __builtin_amdgcn_s_sleep(1);
      }
      if (sdone[t][srow]){
        #pragma unroll
        for (int j2=0;j2<4;++j2){ u32x4 z = {0,0,0,0}; hv[j2] = z; }
      } else {
        #pragma unroll
        for (int j2=0;j2<4;++j2){
          hv[j2][0] &= ~0x00010001u; hv[j2][1] &= ~0x00010001u;
          hv[j2][2] &= ~0x00010001u; hv[j2][3] &= ~0x00010001u;
        }
      }
      #pragma unroll
      for (int j=0;j<4;++j){
        *(u32x4*)(shb + sci*1024 + ((((srow + 16*j)*16)) ^ ((sci&7)<<4))) = hv[j];
      }
    }
    __syncthreads();
    // (c) h @ Whh^T  (A from LDS, B from pinned registers)
    f32x4 a0e = zero4(), a0o = zero4(), a1e = zero4(), a1o = zero4();
    #pragma unroll
    for (int ks=0; ks<16; ++ks){
      bfrag a = *(const bfrag*)(shb + ks*1024 + (loff ^ ((ks&7)<<4)));
      if (ks & 1){ a0o = mfma16(a, wb0[ks], a0o); a1o = mfma16(a, wb1[ks], a1o); }
      else       { a0e = mfma16(a, wb0[ks], a0e); a1e = mfma16(a, wb1[ks], a1e); }
    }
    #pragma unroll
    for (int r2=0;r2<4;++r2){
      int m = (l>>4)*4 + r2;
      sg[w][m][(l&15)]    = a0e[r2] + a0o[r2] + gv0[r2];
      sg[w][m][16+(l&15)] = a1e[r2] + a1o[r2] + gv1[r2];
    }
    __syncthreads();
    // (d) gates + cell + publish tagged h
    {
      int p0 = tid*2; int m = p0>>5, u = p0&31;
      int dn = sdone[t][m];
      float c_0 = dn ? 0.f : sc[m][u];
      float c_1 = dn ? 0.f : sc[m][u+1];
      float i0=sg[0][m][u],   f0=sg[1][m][u],   g0=sg[2][m][u],   o0=sg[3][m][u];
      float i1=sg[0][m][u+1], f1=sg[1][m][u+1], g1=sg[2][m][u+1], o1=sg[3][m][u+1];
      float cn0 = sigm(f0)*c_0 + sigm(i0)*ftanh(g0);
      float cn1 = sigm(f1)*c_1 + sigm(i1)*ftanh(g1);
      float h_0 = sigm(o0)*ftanh(cn0);
      float h_1 = sigm(o1)*ftanh(cn1);
      sc[m][u] = cn0; sc[m][u+1] = cn1;
      uint32_t pk = pk2f(h_0, h_1);
      int p1 = (t+1)&3;
      uint32_t pat = ((uint32_t)(p1&1)) | (((uint32_t)(p1>>1))<<16);
      uint32_t pkT = (pk & ~0x00010001u) | pat;
      __hip_atomic_store(
          hcurT + (size_t)((t+1)&1)*16384 + (size_t)(bb+m)*256 + ((uu+u)>>1),
          pkT, __ATOMIC_RELAXED, __HIP_MEMORY_SCOPE_AGENT);
      *(uint32_t*)(hseq + ((long)t*64 + bb + m)*512 + uu + u) = pk;
      if (t == 79){
        outH[(bb+m)*512 + uu + u]   = h_0;  outH[(bb+m)*512 + uu + u+1] = h_1;
        outC[(bb+m)*512 + uu + u]   = cn0;  outC[(bb+m)*512 + uu + u+1] = cn1;
      }
    }
  }
}

// ---------------------------------------------------------------- fused head2 + dueling combine
__global__ __launch_bounds__(256) void k_qhead(
    const bf16* __restrict__ zav, const bf16* __restrict__ w2cat,
    const float* __restrict__ ab2, const float* __restrict__ vb2,
    float* __restrict__ q)
{
  __shared__ float sq[4][16][33];
  const int tid=threadIdx.x, w=tid>>6, l=tid&63;
  const int s0 = blockIdx.x*64 + w*16;
  f32x4 acc0 = zero4(), acc1 = zero4();
  const int row = l&15;
  #pragma unroll 4
  for (int ks=0; ks<32; ++ks){
    int k = ks*32 + 8*(l>>4);
    bfrag a  = ldg16(zav + (long)(s0+row)*1024 + k);
    bfrag b0 = ldg16(w2cat + (l&15)*1024 + k);
    bfrag b1 = ldg16(w2cat + (16+(l&15))*1024 + k);
    acc0 = mfma16(a, b0, acc0);
    acc1 = mfma16(a, b1, acc1);
  }
  #pragma unroll
  for (int r2=0;r2<4;++r2){
    int m = (l>>4)*4 + r2;
    sq[w][m][l&15]      = acc0[r2];
    sq[w][m][16+(l&15)] = acc1[r2];
  }
  __syncthreads();
  if (l < 16){
    int s = s0 + l;
    float av[18]; float sum = 0.f;
    #pragma unroll
    for (int j=0;j<18;++j){ av[j] = sq[w][l][j] + ab2[j]; sum += av[j]; }
    float val = sq[w][l][18] + vb2[0];
    float mean = sum * (1.f/18.f);
    #pragma unroll
    for (int j=0;j<18;++j) q[(long)s*18 + j] = val + av[j] - mean;
  }
}

// ================================================================ host
extern "C" void kernel_launch(void* const* d_in, const int* in_sizes, int n_in,
                              void* d_out, int out_size, void* d_ws, size_t ws_size,
                              hipStream_t stream)
{
  (void)in_sizes; (void)n_in; (void)out_size;
  const int*   o_in = (const int*)  d_in[0];
  const int*   a_in = (const int*)  d_in[1];
  const float* r_in = (const float*)d_in[2];
  const int*   done = (const int*)  d_in[3];
  const float* h0   = (const float*)d_in[4];
  const float* c0   = (const float*)d_in[5];
  const float* c1w  = (const float*)d_in[6],  *c1b=(const float*)d_in[7];
  const float* c2w  = (const float*)d_in[8],  *c2b=(const float*)d_in[9];
  const float* c3w  = (const float*)d_in[10], *c3b=(const float*)d_in[11];
  const float* fcw  = (const float*)d_in[12], *fcb=(const float*)d_in[13];
  const float* Wih  = (const float*)d_in[14], *WhhF=(const float*)d_in[15];
  const float* bih  = (const float*)d_in[16], *bhh=(const float*)d_in[17];
  const float* aw1  = (const float*)d_in[18], *ab1=(const float*)d_in[19];
  const float* aw2  = (const float*)d_in[20], *ab2=(const float*)d_in[21];
  const float* vw1  = (const float*)d_in[22], *vb1=(const float*)d_in[23];
  const float* vw2  = (const float*)d_in[24], *vb2=(const float*)d_in[25];

  char* ws = (char*)d_ws;
  size_t off = 0;
  auto alloc = [&](size_t b){ size_t p = off; off = (off + b + 255) & ~(size_t)255; return p; };
  bf16*  act2   = (bf16*) (ws + alloc(53084160));   // 5120 x 5184   (G aliases later)
  bf16*  act3   = (bf16*) (ws + alloc(32768000));   // 5120 x 3200   (zav aliases later)
  bf16*  hidden = (bf16*) (ws + alloc(5242880));    // 5120 x 512    (hseq aliases later)
  uint32_t* hcurT = (uint32_t*)(ws + alloc(131072));// 2 x 64 x 256 tagged bf16-pairs
  bf16*  w1b    = (bf16*) (ws + alloc(4096));
  bf16*  w2r    = (bf16*) (ws + alloc(65536));
  bf16*  w3r    = (bf16*) (ws + alloc(73728));
  bf16*  fcwr   = (bf16*) (ws + alloc(3276800));
  bf16*  Wx     = (bf16*) (ws + alloc(2097152));
  bf16*  Whh    = (bf16*) (ws + alloc(2097152));
  float* biasL  = (float*)(ws + alloc(8192));
  float* Wr     = (float*)(ws + alloc(8192));
  float* Wa     = (float*)(ws + alloc(147456));
  bf16*  headw1 = (bf16*) (ws + alloc(1048576));
  float* headb1 = (float*)(ws + alloc(4096));
  bf16*  w2cat  = (bf16*) (ws + alloc(65536));
  if (off > ws_size) return;

  bf16*  G    = act2;            // 21MB <= 53.1MB (bf16 gates)
  bf16*  hseq = hidden;
  bf16*  zav  = act3;            // 10.5MB <= 32.8MB

  float* qout = (float*)d_out;
  float* outH = qout + 92160;
  float* outC = qout + 124928;

  k_prep<<<17340, 256, 0, stream>>>(c1w, c2w, c3w, fcw, Wih, WhhF, bih, bhh,
      aw1, aw2, vw1, vw2, h0, ab1, vb1, w1b, w2r, w3r, fcwr, Wx, Whh,
      biasL, Wr, Wa, headw1, headb1, w2cat, hcurT);

  k_conv12<<<2560, 512, 0, stream>>>(o_in, w1b, c1b, w2r, c2b, act2);
  k_conv3<<<1280, 256, 0, stream>>>(act2, w3r, c3b, act3);
  k_gemm<true,true><<<dim3(80,4), 256, 0, stream>>>(
      act3, 3200, fcwr, 3200, fcb, nullptr, hidden, 512, 3200,
      nullptr, nullptr, nullptr, nullptr);
  // G = hidden @ Wx^T + bias + r*Wr + Wa[a]  -> bf16
  k_gemm<false,true><<<dim3(80,16), 256, 0, stream>>>(
      hidden, 512, Wx, 512, biasL, nullptr, G, 2048, 512,
      r_in, a_in, Wr, Wa);

  k_lstm<<<64, 256, 0, stream>>>(G, done, c0, Whh, hcurT, hseq, outH, outC);

  k_gemm<true,true><<<dim3(80,8), 256, 0, stream>>>(
      hseq, 512, headw1, 512, headb1, nullptr, zav, 1024, 512,
      nullptr, nullptr, nullptr, nullptr);
  k_qhead<<<80, 256, 0, stream>>>(zav, w2cat, ab2, vb2, qout);
}

// Round 16
// 605.755 us; speedup vs baseline: 1.1670x; 1.1670x over previous
//
#include <hip/hip_runtime.h>
#include <hip/hip_bf16.h>
#include <stdint.h>

typedef __bf16 bf16;
typedef __bf16 bfrag __attribute__((ext_vector_type(8)));
typedef short s16x8 __attribute__((ext_vector_type(8)));
typedef float f32x4 __attribute__((ext_vector_type(4)));
typedef float f32x16 __attribute__((ext_vector_type(16)));
typedef uint32_t u32x4 __attribute__((ext_vector_type(4)));

#define DEV __device__ __forceinline__

DEV bfrag ldg16(const bf16* p){ return *(const bfrag*)p; }

struct U64x2 { uint64_t a, b; };
DEV bfrag ld2x8(const bf16* p){
  U64x2 t; t.a = *(const uint64_t*)p; t.b = *(const uint64_t*)(p+4);
  return __builtin_bit_cast(bfrag, t);
}
// 16B from LDS as 4 dword loads (4B-aligned safe — used with 76B pixel stride)
DEV bfrag ld4x4(const char* p){
  u32x4 t;
  t[0] = *(const uint32_t*)p;
  t[1] = *(const uint32_t*)(p+4);
  t[2] = *(const uint32_t*)(p+8);
  t[3] = *(const uint32_t*)(p+12);
  return __builtin_bit_cast(bfrag, t);
}

DEV f32x4  mfma16(bfrag a, bfrag b, f32x4  c){ return __builtin_amdgcn_mfma_f32_16x16x32_bf16(a,b,c,0,0,0); }
DEV f32x16 mfma32(bfrag a, bfrag b, f32x16 c){ return __builtin_amdgcn_mfma_f32_32x32x16_bf16(a,b,c,0,0,0); }

DEV f32x16 zero16(){
  f32x16 v;
  for(int i=0;i<16;++i) v[i]=0.f;
  return v;
}
DEV f32x4 zero4(){
  f32x4 v;
  for(int i=0;i<4;++i) v[i]=0.f;
  return v;
}

DEV float sigm(float x){ return 1.0f/(1.0f+__expf(-x)); }
DEV float ftanh(float x){ float e = __expf(2.f*x); return 1.f - 2.f/(e+1.f); }

// coherent (L1+L2-bypass) 16B load — reads straight from the IF coherence point
DEV u32x4 ldcg4(const uint32_t* p){
  u32x4 r;
  asm volatile("global_load_dwordx4 %0, %1, off sc0 sc1" : "=v"(r) : "v"(p));
  return r;
}

DEV uint32_t pk2f(float a, float b){
  bf16 x = (bf16)a, y = (bf16)b;
  return (uint32_t)__builtin_bit_cast(uint16_t,x) | ((uint32_t)__builtin_bit_cast(uint16_t,y)<<16);
}

// async global->LDS 16B: per-lane global src, wave-uniform LDS base + lane*16
DEV void gl_lds16(const bf16* g, void* l){
  __builtin_amdgcn_global_load_lds(
      (const __attribute__((address_space(1))) uint32_t*)g,
      (__attribute__((address_space(3))) uint32_t*)l, 16, 0, 0);
}

// ---------------------------------------------------------------- k_prep
__global__ __launch_bounds__(256) void k_prep(
    const float* __restrict__ c1w, const float* __restrict__ c2w,
    const float* __restrict__ c3w, const float* __restrict__ fcw,
    const float* __restrict__ Wih, const float* __restrict__ WhhF,
    const float* __restrict__ bih, const float* __restrict__ bhh,
    const float* __restrict__ aw1, const float* __restrict__ aw2,
    const float* __restrict__ vw1, const float* __restrict__ vw2,
    const float* __restrict__ h0, const float* __restrict__ ab1,
    const float* __restrict__ vb1,
    bf16* w1b, bf16* w2r, bf16* w3r, bf16* fcwr, bf16* Wx, bf16* Whh,
    float* biasL, float* Wr, float* Wa, bf16* headw1, float* headb1,
    bf16* w2cat, uint32_t* hcurT)
{
  long i = (long)blockIdx.x*256 + threadIdx.x;
  if (i < 2048){ int co=(int)(i>>6), k=(int)(i&63);
    w1b[i] = (bf16)(c1w[co*64+k]*(1.f/255.f)); return; } i -= 2048;
  if (i < 32768){ int o=(int)(i>>9), k=(int)(i&511);
    int ky=k>>7, kx=(k>>5)&3, ci=k&31;
    w2r[i] = (bf16)c2w[((o*32+ci)*4+ky)*4+kx]; return; } i -= 32768;
  if (i < 36864){ int o=(int)(i/576), k=(int)(i%576);
    int ky=k/192, rem=k-ky*192, kx=rem>>6, ci=rem&63;
    w3r[i] = (bf16)c3w[((o*64+ci)*3+ky)*3+kx]; return; } i -= 36864;
  if (i < 1605632){ // fcw: source-coalesced read, scattered write
    int o=(int)(i/3136), rem=(int)(i%3136);
    int ci=rem/49, yx=rem-ci*49, y=yx/7, x=yx-y*7;
    fcwr[o*3200 + y*448 + x*64 + ci] = (bf16)fcw[i]; return; } i -= 1605632;
  if (i < 32768){ int o=(int)(i>>6), k=(int)(i&63);
    fcwr[o*3200 + 3136 + k] = (bf16)0.f; return; } i -= 32768;
  if (i < 1048576){ int n=(int)(i>>9), k=(int)(i&511);
    Wx[i] = (bf16)Wih[n*531+k]; return; } i -= 1048576;
  if (i < 1048576){ int n=(int)(i>>9), k=(int)(i&511);
    Whh[i] = (bf16)WhhF[n*512+k]; return; } i -= 1048576;
  if (i < 2048){ biasL[i] = bih[i]+bhh[i]; return; } i -= 2048;
  if (i < 2048){ Wr[i] = Wih[i*531+512]; return; } i -= 2048;
  if (i < 36864){ int j=(int)(i>>11), n=(int)(i&2047);
    Wa[i] = Wih[n*531+513+j]; return; } i -= 36864;
  if (i < 524288){ headw1[i] = (bf16)(i<262144 ? aw1[i] : vw1[i-262144]); return; } i -= 524288;
  if (i < 1024){ headb1[i] = (i<512) ? ab1[i] : vb1[i-512]; return; } i -= 1024;
  if (i < 32768){ int n=(int)(i>>10), k=(int)(i&1023);
    float v = 0.f;
    if (n<18 && k<512) v = aw2[n*512+k];
    else if (n==18 && k>=512) v = vw2[k-512];
    w2cat[i] = (bf16)v; return; } i -= 32768;
  if (i < 32768){
    if (i < 16384){
      int row = (int)(i>>8), wd = (int)(i&255);
      uint32_t pk = pk2f(h0[row*512 + wd*2], h0[row*512 + wd*2 + 1]);
      hcurT[i] = pk & ~0x00010001u;
    } else {
      hcurT[i] = 0x00010000u;
    }
    return;
  }
}

// ---------------------------------------------------------------- conv1+conv2 fused
// 256 threads, 2 images/block, act1 in LDS at 76B pixel stride.
__global__ __launch_bounds__(256,2) void k_conv12(
    const int* __restrict__ o, const bf16* __restrict__ w1b,
    const float* __restrict__ c1b, const bf16* __restrict__ w2r,
    const float* __restrict__ c2b, bf16* __restrict__ act2)
{
  __shared__ bf16 lact[2][15200];    // 2 img x 400 px x 76B (60800 B)
  const int tid = threadIdx.x;
  const int w = tid>>6, l = tid&63;
  const int img = w>>1, h = w&1;
  const long gimg = (long)blockIdx.x*2 + img;
  const int* ip = o + gimg*7056;
  char* lw = (char*)&lact[img][0];
  {
    bfrag bw[4];
    #pragma unroll
    for (int ks=0;ks<4;++ks) bw[ks] = ldg16(w1b + (l&31)*64 + ks*16 + 8*(l>>5));
    const float bias = c1b[l&31];
    for (int mt=h; mt<13; mt+=2){
      f32x16 acc = zero16();
      int m0 = mt*32 + (l&31);
      int p  = m0>399 ? 399 : m0;
      int oy = p/20, ox = p - oy*20;
      #pragma unroll
      for (int ks=0;ks<4;++ks){
        int ky = 2*ks + (l>>5);
        const int* q = ip + (oy*4+ky)*84 + ox*4;
        int4 i0 = *(const int4*)q;
        int4 i1 = *(const int4*)(q+4);
        bfrag a;
        a[0]=(bf16)(float)i0.x; a[1]=(bf16)(float)i0.y;
        a[2]=(bf16)(float)i0.z; a[3]=(bf16)(float)i0.w;
        a[4]=(bf16)(float)i1.x; a[5]=(bf16)(float)i1.y;
        a[6]=(bf16)(float)i1.z; a[7]=(bf16)(float)i1.w;
        acc = mfma32(a, bw[ks], acc);
      }
      #pragma unroll
      for (int r2=0;r2<16;++r2){
        int row = (r2&3) + 8*(r2>>2) + 4*(l>>5);
        int m = mt*32 + row;
        if (m < 400){
          float v = acc[r2] + bias; v = v>0.f ? v : 0.f;
          *(bf16*)(lw + m*76 + (l&31)*2) = (bf16)v;
        }
      }
    }
  }
  __syncthreads();
  {
    f32x16 acc2[3];
    #pragma unroll
    for (int a2=0;a2<3;++a2) acc2[a2]=zero16();
    int pb[3];
    #pragma unroll
    for (int mt=0;mt<3;++mt){
      int m = mt*32 + (l&31); int p = m>80 ? 80 : m;
      int oy = p/9, ox = p - oy*9;
      pb[mt] = (oy*2)*20 + ox*2;
    }
    #pragma unroll 4
    for (int ks=0; ks<32; ++ks){
      int k  = ks*16 + 8*(l>>5);
      int ky = k>>7, kx = (k>>5)&3, ci = k&31;
      bfrag b0 = ldg16(w2r + (32*h + (l&31))*512 + k);
      #pragma unroll
      for (int mt=0; mt<3; ++mt){
        int p2 = pb[mt] + ky*20 + kx;
        bfrag a = ld4x4(lw + p2*76 + ci*2);
        acc2[mt] = mfma32(a, b0, acc2[mt]);
      }
    }
    const float bias2 = c2b[32*h + (l&31)];
    #pragma unroll
    for (int mt=0; mt<3; ++mt){
      #pragma unroll
      for (int r2=0;r2<16;++r2){
        int row = (r2&3) + 8*(r2>>2) + 4*(l>>5);
        int m = mt*32 + row;
        if (m < 81){
          float v = acc2[mt][r2] + bias2; v = v>0.f ? v : 0.f;
          act2[gimg*5184 + m*64 + 32*h + (l&31)] = (bf16)v;
        }
      }
    }
  }
}

// ---------------------------------------------------------------- conv3
__global__ __launch_bounds__(256,2) void k_conv3(
    const bf16* __restrict__ act2, const bf16* __restrict__ w3r,
    const float* __restrict__ c3b, bf16* __restrict__ act3)
{
  const int tid=threadIdx.x, w=tid>>6, l=tid&63;
  const long img = (long)blockIdx.x*4 + w;
  const bf16* A = act2 + img*5184;
  f32x16 acc[2][2];
  #pragma unroll
  for(int a2=0;a2<2;++a2){ acc[a2][0]=zero16(); acc[a2][1]=zero16(); }
  #pragma unroll 4
  for (int ks=0; ks<36; ++ks){
    int k  = ks*16 + 8*(l>>5);
    int ky = k/192, rem = k - ky*192, kx = rem>>6, ci = rem&63;
    bfrag b0 = ldg16(w3r + (l&31)*576 + k);
    bfrag b1 = ldg16(w3r + (32+(l&31))*576 + k);
    #pragma unroll
    for (int mt=0; mt<2; ++mt){
      int m = mt*32 + (l&31); int p = m>48 ? 48 : m;
      int oy = p/7, ox = p - oy*7;
      bfrag a = ldg16(A + ((oy+ky)*9 + (ox+kx))*64 + ci);
      acc[mt][0] = mfma32(a, b0, acc[mt][0]);
      acc[mt][1] = mfma32(a, b1, acc[mt][1]);
    }
  }
  const float bias0 = c3b[l&31], bias1 = c3b[32+(l&31)];
  #pragma unroll
  for (int mt=0; mt<2; ++mt){
    #pragma unroll
    for (int r2=0;r2<16;++r2){
      int row = (r2&3) + 8*(r2>>2) + 4*(l>>5);
      int m = mt*32 + row;
      if (m < 50){
        float v0 = 0.f, v1 = 0.f;
        if (m < 49){
          v0 = acc[mt][0][r2] + bias0; v0 = v0>0.f ? v0 : 0.f;
          v1 = acc[mt][1][r2] + bias1; v1 = v1>0.f ? v1 : 0.f;
        }
        act3[img*3200 + m*64 + (l&31)]      = (bf16)v0;
        act3[img*3200 + m*64 + 32 + (l&31)] = (bf16)v1;
      }
    }
  }
}

// ---------------------------------------------------------------- generic GEMM
template<bool RELU, bool OUTBF16>
__global__ __launch_bounds__(256,4) void k_gemm(
    const bf16* __restrict__ A, long lda,
    const bf16* __restrict__ W, long ldb,
    const float* __restrict__ bias,
    float* __restrict__ outF, bf16* __restrict__ outB, long ldo, int K,
    const float* __restrict__ fixR, const int* __restrict__ fixA,
    const float* __restrict__ fixWr, const float* __restrict__ fixWa)
{
  __shared__ bf16 sA[8192];
  char* sb = (char*)sA;
  const int tid=threadIdx.x, w=tid>>6, l=tid&63;
  const int m0 = blockIdx.x*64, n0 = blockIdx.y*128;
  f32x16 acc[2]; acc[0]=zero16(); acc[1]=zero16();
  const int mt = w&1;
  const int rowa = mt*32 + (l&31);
  for (int kc=0; kc<K; kc+=128){
    __syncthreads();
    #pragma unroll
    for (int j=0;j<4;++j){
      int idx = j*64 + l;
      int row = w*16 + (idx>>4);
      int seg = idx&15;
      const bf16* gp = A + (long)(m0+row)*lda + kc + (((seg*16) ^ ((row&15)<<4))>>1);
      gl_lds16(gp, sb + w*4096 + j*1024);
    }
    asm volatile("s_waitcnt vmcnt(0)" ::: "memory");
    __syncthreads();
    #pragma unroll
    for (int ks=0; ks<8; ++ks){
      bfrag a = *(const bfrag*)(sb + rowa*256 + ((ks*32 + (l>>5)*16) ^ ((rowa&15)<<4)));
      #pragma unroll
      for (int j=0;j<2;++j){
        int nt = (w>>1)*2 + j;
        bfrag b = ldg16(W + (long)(n0 + nt*32 + (l&31))*ldb + kc + ks*16 + 8*(l>>5));
        acc[j] = mfma32(a, b, acc[j]);
      }
    }
  }
  #pragma unroll
  for (int j=0;j<2;++j){
    int nt = (w>>1)*2 + j;
    int gc = n0 + nt*32 + (l&31);
    float bv = bias ? bias[gc] : 0.f;
    float wrv = fixR ? fixWr[gc] : 0.f;
    #pragma unroll
    for (int r2=0;r2<16;++r2){
      int row = (r2&3) + 8*(r2>>2) + 4*(l>>5);
      long gr = m0 + mt*32 + row;
      float v = acc[j][r2] + bv;
      if (fixR) v += fixR[gr]*wrv + fixWa[(long)fixA[gr]*2048 + gc];
      if (RELU) v = v>0.f ? v : 0.f;
      if (OUTBF16) outB[gr*ldo + gc] = (bf16)v;
      else         outF[gr*ldo + gc] = v;
    }
  }
}

// ---------------------------------------------------------------- LSTM recurrence (single 80-step dispatch)
// W_hh pinned in VGPRs; sc1 tag-in-data h exchange; G read as bf16.
__global__ __launch_bounds__(256,1) void k_lstm(
    const bf16* __restrict__ G, const int* __restrict__ done,
    const float* __restrict__ c0, const bf16* __restrict__ Whh,
    uint32_t* __restrict__ hcurT, bf16* __restrict__ hseq,
    float* __restrict__ outH, float* __restrict__ outC)
{
  __shared__ bf16 sh2[8192];         // 16 frags x 64 lanes x 8bf16 (16KB)
  __shared__ float sg[4][16][33];
  __shared__ float sc[16][33];
  __shared__ char  sdone[80][16];
  const int tid=threadIdx.x, w=tid>>6, l=tid&63;
  const int blk=blockIdx.x;
  const int grp=(blk&7)>>1, jj=((blk&1)<<3)|(blk>>3);
  const int bb = grp*16, uu = jj*32;

  for (int p=tid; p<512; p+=256){ int m=p>>5, u=p&31; sc[m][u] = c0[(bb+m)*512 + uu + u]; }
  for (int p=tid; p<1280; p+=256){ int t=p>>4, m=p&15; sdone[t][m] = (char)done[t*64 + bb + m]; }

  // W_hh fragments -> registers, pinned (cannot be rematerialized past the asm)
  bfrag wb0[16], wb1[16];
  {
    const long row0 = (long)w*512 + uu + (l&15);
    #pragma unroll
    for (int ks=0; ks<16; ++ks){
      int k = ks*32 + 8*(l>>4);
      wb0[ks] = ldg16(Whh + row0*512 + k);
      wb1[ks] = ldg16(Whh + (row0+16)*512 + k);
      asm volatile("" : "+v"(wb0[ks]), "+v"(wb1[ks]));
    }
  }

  char* shb = (char*)sh2;
  const int loff = l*16;
  const int srow  = tid>>4;
  const int sci   = tid&15;

  __syncthreads();

  for (int t=0; t<80; ++t){
    // (a) G loads for this step — independent of h, overlap the poll
    float gv0[4], gv1[4];
    {
      const bf16* Gt = G + ((long)t*64 + bb)*2048 + w*512 + uu;
      #pragma unroll
      for (int r2=0;r2<4;++r2){
        int m2 = (l>>4)*4 + r2;
        gv0[r2] = (float)Gt[(long)m2*2048 + (l&15)];
        gv1[r2] = (float)Gt[(long)m2*2048 + 16 + (l&15)];
      }
    }
    __builtin_amdgcn_sched_barrier(0);
    // (b) poll tagged bf16-pair h words for step t
    {
      const uint32_t* hb = hcurT + (size_t)(t&1)*16384 + (size_t)(bb+srow)*256 + sci*16;
      u32x4 hv[4];
      const uint32_t expPat = ((uint32_t)(t&1)) | (((uint32_t)((t>>1)&1))<<16);
      for (;;){
        #pragma unroll
        for (int j2=0;j2<4;++j2) hv[j2] = ldcg4(hb + j2*4);
        asm volatile("s_waitcnt vmcnt(0)" ::: "memory");
        bool ok = true;
        #pragma unroll
        for (int j2=0;j2<4;++j2){
          ok &= ((hv[j2][0]&0x00010001u)==expPat) & ((hv[j2][1]&0x00010001u)==expPat)
              & ((hv[j2][2]&0x00010001u)==expPat) & ((hv[j2][3]&0x00010001u)==expPat);
        }
        if (__all(ok)) break;
        __builtin_amdgcn_s_sleep(1);
      }
      if (sdone[t][srow]){
        #pragma unroll
        for (int j2=0;j2<4;++j2){ u32x4 z = {0,0,0,0}; hv[j2] = z; }
      } else {
        #pragma unroll
        for (int j2=0;j2<4;++j2){
          hv[j2][0] &= ~0x00010001u; hv[j2][1] &= ~0x00010001u;
          hv[j2][2] &= ~0x00010001u; hv[j2][3] &= ~0x00010001u;
        }
      }
      #pragma unroll
      for (int j=0;j<4;++j){
        *(u32x4*)(shb + sci*1024 + ((((srow + 16*j)*16)) ^ ((sci&7)<<4))) = hv[j];
      }
    }
    __syncthreads();
    // (c) h @ Whh^T  (A from LDS, B from pinned registers)
    f32x4 a0e = zero4(), a0o = zero4(), a1e = zero4(), a1o = zero4();
    #pragma unroll
    for (int ks=0; ks<16; ++ks){
      bfrag a = *(const bfrag*)(shb + ks*1024 + (loff ^ ((ks&7)<<4)));
      if (ks & 1){ a0o = mfma16(a, wb0[ks], a0o); a1o = mfma16(a, wb1[ks], a1o); }
      else       { a0e = mfma16(a, wb0[ks], a0e); a1e = mfma16(a, wb1[ks], a1e); }
    }
    #pragma unroll
    for (int r2=0;r2<4;++r2){
      int m = (l>>4)*4 + r2;
      sg[w][m][(l&15)]    = a0e[r2] + a0o[r2] + gv0[r2];
      sg[w][m][16+(l&15)] = a1e[r2] + a1o[r2] + gv1[r2];
    }
    __syncthreads();
    // (d) gates + cell + publish tagged h
    {
      int p0 = tid*2; int m = p0>>5, u = p0&31;
      int dn = sdone[t][m];
      float c_0 = dn ? 0.f : sc[m][u];
      float c_1 = dn ? 0.f : sc[m][u+1];
      float i0=sg[0][m][u],   f0=sg[1][m][u],   g0=sg[2][m][u],   o0=sg[3][m][u];
      float i1=sg[0][m][u+1], f1=sg[1][m][u+1], g1=sg[2][m][u+1], o1=sg[3][m][u+1];
      float cn0 = sigm(f0)*c_0 + sigm(i0)*ftanh(g0);
      float cn1 = sigm(f1)*c_1 + sigm(i1)*ftanh(g1);
      float h_0 = sigm(o0)*ftanh(cn0);
      float h_1 = sigm(o1)*ftanh(cn1);
      sc[m][u] = cn0; sc[m][u+1] = cn1;
      uint32_t pk = pk2f(h_0, h_1);
      int p1 = (t+1)&3;
      uint32_t pat = ((uint32_t)(p1&1)) | (((uint32_t)(p1>>1))<<16);
      uint32_t pkT = (pk & ~0x00010001u) | pat;
      __hip_atomic_store(
          hcurT + (size_t)((t+1)&1)*16384 + (size_t)(bb+m)*256 + ((uu+u)>>1),
          pkT, __ATOMIC_RELAXED, __HIP_MEMORY_SCOPE_AGENT);
      *(uint32_t*)(hseq + ((long)t*64 + bb + m)*512 + uu + u) = pk;
      if (t == 79){
        outH[(bb+m)*512 + uu + u]   = h_0;  outH[(bb+m)*512 + uu + u+1] = h_1;
        outC[(bb+m)*512 + uu + u]   = cn0;  outC[(bb+m)*512 + uu + u+1] = cn1;
      }
    }
  }
}

// ---------------------------------------------------------------- fused head2 + dueling combine
__global__ __launch_bounds__(256) void k_qhead(
    const bf16* __restrict__ zav, const bf16* __restrict__ w2cat,
    const float* __restrict__ ab2, const float* __restrict__ vb2,
    float* __restrict__ q)
{
  __shared__ float sq[4][16][33];
  const int tid=threadIdx.x, w=tid>>6, l=tid&63;
  const int s0 = blockIdx.x*64 + w*16;
  f32x4 acc0 = zero4(), acc1 = zero4();
  const int row = l&15;
  #pragma unroll 4
  for (int ks=0; ks<32; ++ks){
    int k = ks*32 + 8*(l>>4);
    bfrag a  = ldg16(zav + (long)(s0+row)*1024 + k);
    bfrag b0 = ldg16(w2cat + (l&15)*1024 + k);
    bfrag b1 = ldg16(w2cat + (16+(l&15))*1024 + k);
    acc0 = mfma16(a, b0, acc0);
    acc1 = mfma16(a, b1, acc1);
  }
  #pragma unroll
  for (int r2=0;r2<4;++r2){
    int m = (l>>4)*4 + r2;
    sq[w][m][l&15]      = acc0[r2];
    sq[w][m][16+(l&15)] = acc1[r2];
  }
  __syncthreads();
  if (l < 16){
    int s = s0 + l;
    float av[18]; float sum = 0.f;
    #pragma unroll
    for (int j=0;j<18;++j){ av[j] = sq[w][l][j] + ab2[j]; sum += av[j]; }
    float val = sq[w][l][18] + vb2[0];
    float mean = sum * (1.f/18.f);
    #pragma unroll
    for (int j=0;j<18;++j) q[(long)s*18 + j] = val + av[j] - mean;
  }
}

// ================================================================ host
extern "C" void kernel_launch(void* const* d_in, const int* in_sizes, int n_in,
                              void* d_out, int out_size, void* d_ws, size_t ws_size,
                              hipStream_t stream)
{
  (void)in_sizes; (void)n_in; (void)out_size;
  const int*   o_in = (const int*)  d_in[0];
  const int*   a_in = (const int*)  d_in[1];
  const float* r_in = (const float*)d_in[2];
  const int*   done = (const int*)  d_in[3];
  const float* h0   = (const float*)d_in[4];
  const float* c0   = (const float*)d_in[5];
  const float* c1w  = (const float*)d_in[6],  *c1b=(const float*)d_in[7];
  const float* c2w  = (const float*)d_in[8],  *c2b=(const float*)d_in[9];
  const float* c3w  = (const float*)d_in[10], *c3b=(const float*)d_in[11];
  const float* fcw  = (const float*)d_in[12], *fcb=(const float*)d_in[13];
  const float* Wih  = (const float*)d_in[14], *WhhF=(const float*)d_in[15];
  const float* bih  = (const float*)d_in[16], *bhh=(const float*)d_in[17];
  const float* aw1  = (const float*)d_in[18], *ab1=(const float*)d_in[19];
  const float* aw2  = (const float*)d_in[20], *ab2=(const float*)d_in[21];
  const float* vw1  = (const float*)d_in[22], *vb1=(const float*)d_in[23];
  const float* vw2  = (const float*)d_in[24], *vb2=(const float*)d_in[25];

  char* ws = (char*)d_ws;
  size_t off = 0;
  auto alloc = [&](size_t b){ size_t p = off; off = (off + b + 255) & ~(size_t)255; return p; };
  bf16*  act2   = (bf16*) (ws + alloc(53084160));   // 5120 x 5184   (G aliases later)
  bf16*  act3   = (bf16*) (ws + alloc(32768000));   // 5120 x 3200   (zav aliases later)
  bf16*  hidden = (bf16*) (ws + alloc(5242880));    // 5120 x 512    (hseq aliases later)
  uint32_t* hcurT = (uint32_t*)(ws + alloc(131072));// 2 x 64 x 256 tagged bf16-pairs
  bf16*  w1b    = (bf16*) (ws + alloc(4096));
  bf16*  w2r    = (bf16*) (ws + alloc(65536));
  bf16*  w3r    = (bf16*) (ws + alloc(73728));
  bf16*  fcwr   = (bf16*) (ws + alloc(3276800));
  bf16*  Wx     = (bf16*) (ws + alloc(2097152));
  bf16*  Whh    = (bf16*) (ws + alloc(2097152));
  float* biasL  = (float*)(ws + alloc(8192));
  float* Wr     = (float*)(ws + alloc(8192));
  float* Wa     = (float*)(ws + alloc(147456));
  bf16*  headw1 = (bf16*) (ws + alloc(1048576));
  float* headb1 = (float*)(ws + alloc(4096));
  bf16*  w2cat  = (bf16*) (ws + alloc(65536));
  if (off > ws_size) return;

  bf16*  G    = act2;            // 21MB <= 53.1MB (bf16 gates)
  bf16*  hseq = hidden;
  bf16*  zav  = act3;            // 10.5MB <= 32.8MB

  float* qout = (float*)d_out;
  float* outH = qout + 92160;
  float* outC = qout + 124928;

  k_prep<<<17340, 256, 0, stream>>>(c1w, c2w, c3w, fcw, Wih, WhhF, bih, bhh,
      aw1, aw2, vw1, vw2, h0, ab1, vb1, w1b, w2r, w3r, fcwr, Wx, Whh,
      biasL, Wr, Wa, headw1, headb1, w2cat, hcurT);

  k_conv12<<<2560, 256, 0, stream>>>(o_in, w1b, c1b, w2r, c2b, act2);
  k_conv3<<<1280, 256, 0, stream>>>(act2, w3r, c3b, act3);
  k_gemm<true,true><<<dim3(80,4), 256, 0, stream>>>(
      act3, 3200, fcwr, 3200, fcb, nullptr, hidden, 512, 3200,
      nullptr, nullptr, nullptr, nullptr);
  // G = hidden @ Wx^T + bias + r*Wr + Wa[a]  -> bf16
  k_gemm<false,true><<<dim3(80,16), 256, 0, stream>>>(
      hidden, 512, Wx, 512, biasL, nullptr, G, 2048, 512,
      r_in, a_in, Wr, Wa);

  k_lstm<<<64, 256, 0, stream>>>(G, done, c0, Whh, hcurT, hseq, outH, outC);

  k_gemm<true,true><<<dim3(80,8), 256, 0, stream>>>(
      hseq, 512, headw1, 512, headb1, nullptr, zav, 1024, 512,
      nullptr, nullptr, nullptr, nullptr);
  k_qhead<<<80, 256, 0, stream>>>(zav, w2cat, ab2, vb2, qout);
}

// Round 17
// 600.247 us; speedup vs baseline: 1.1777x; 1.0092x over previous
//
#include <hip/hip_runtime.h>
#include <hip/hip_bf16.h>
#include <stdint.h>

typedef __bf16 bf16;
typedef __bf16 bfrag __attribute__((ext_vector_type(8)));
typedef short s16x8 __attribute__((ext_vector_type(8)));
typedef float f32x4 __attribute__((ext_vector_type(4)));
typedef float f32x16 __attribute__((ext_vector_type(16)));
typedef uint32_t u32x4 __attribute__((ext_vector_type(4)));

#define DEV __device__ __forceinline__

DEV bfrag ldg16(const bf16* p){ return *(const bfrag*)p; }

struct U64x2 { uint64_t a, b; };
DEV bfrag ld2x8(const bf16* p){
  U64x2 t; t.a = *(const uint64_t*)p; t.b = *(const uint64_t*)(p+4);
  return __builtin_bit_cast(bfrag, t);
}

DEV f32x4  mfma16(bfrag a, bfrag b, f32x4  c){ return __builtin_amdgcn_mfma_f32_16x16x32_bf16(a,b,c,0,0,0); }
DEV f32x16 mfma32(bfrag a, bfrag b, f32x16 c){ return __builtin_amdgcn_mfma_f32_32x32x16_bf16(a,b,c,0,0,0); }

DEV f32x16 zero16(){
  f32x16 v;
  for(int i=0;i<16;++i) v[i]=0.f;
  return v;
}
DEV f32x4 zero4(){
  f32x4 v;
  for(int i=0;i<4;++i) v[i]=0.f;
  return v;
}

DEV float sigm(float x){ return 1.0f/(1.0f+__expf(-x)); }
DEV float ftanh(float x){ float e = __expf(2.f*x); return 1.f - 2.f/(e+1.f); }

// coherent (L1+L2-bypass) 16B load — reads straight from the IF coherence point
DEV u32x4 ldcg4(const uint32_t* p){
  u32x4 r;
  asm volatile("global_load_dwordx4 %0, %1, off sc0 sc1" : "=v"(r) : "v"(p));
  return r;
}

DEV uint32_t pk2f(float a, float b){
  bf16 x = (bf16)a, y = (bf16)b;
  return (uint32_t)__builtin_bit_cast(uint16_t,x) | ((uint32_t)__builtin_bit_cast(uint16_t,y)<<16);
}

// async global->LDS 16B: per-lane global src, wave-uniform LDS base + lane*16
DEV void gl_lds16(const bf16* g, void* l){
  __builtin_amdgcn_global_load_lds(
      (const __attribute__((address_space(1))) uint32_t*)g,
      (__attribute__((address_space(3))) uint32_t*)l, 16, 0, 0);
}

// ---------------------------------------------------------------- k_prep
__global__ __launch_bounds__(256) void k_prep(
    const float* __restrict__ c1w, const float* __restrict__ c2w,
    const float* __restrict__ c3w, const float* __restrict__ fcw,
    const float* __restrict__ Wih, const float* __restrict__ WhhF,
    const float* __restrict__ bih, const float* __restrict__ bhh,
    const float* __restrict__ aw1, const float* __restrict__ aw2,
    const float* __restrict__ vw1, const float* __restrict__ vw2,
    const float* __restrict__ h0, const float* __restrict__ ab1,
    const float* __restrict__ vb1,
    bf16* w1b, bf16* w2r, bf16* w3r, bf16* fcwr, bf16* Wx, bf16* Whh,
    float* biasL, float* Wr, float* Wa, bf16* headw1, float* headb1,
    bf16* w2cat, uint32_t* hcurT)
{
  long i = (long)blockIdx.x*256 + threadIdx.x;
  if (i < 2048){ int co=(int)(i>>6), k=(int)(i&63);
    w1b[i] = (bf16)(c1w[co*64+k]*(1.f/255.f)); return; } i -= 2048;
  if (i < 32768){ int o=(int)(i>>9), k=(int)(i&511);
    int ky=k>>7, kx=(k>>5)&3, ci=k&31;
    w2r[i] = (bf16)c2w[((o*32+ci)*4+ky)*4+kx]; return; } i -= 32768;
  if (i < 36864){ int o=(int)(i/576), k=(int)(i%576);
    int ky=k/192, rem=k-ky*192, kx=rem>>6, ci=rem&63;
    w3r[i] = (bf16)c3w[((o*64+ci)*3+ky)*3+kx]; return; } i -= 36864;
  if (i < 1605632){ // fcw: source-coalesced read, scattered write
    int o=(int)(i/3136), rem=(int)(i%3136);
    int ci=rem/49, yx=rem-ci*49, y=yx/7, x=yx-y*7;
    fcwr[o*3200 + y*448 + x*64 + ci] = (bf16)fcw[i]; return; } i -= 1605632;
  if (i < 32768){ int o=(int)(i>>6), k=(int)(i&63);
    fcwr[o*3200 + 3136 + k] = (bf16)0.f; return; } i -= 32768;
  if (i < 1048576){ int n=(int)(i>>9), k=(int)(i&511);
    Wx[i] = (bf16)Wih[n*531+k]; return; } i -= 1048576;
  if (i < 1048576){ int n=(int)(i>>9), k=(int)(i&511);
    Whh[i] = (bf16)WhhF[n*512+k]; return; } i -= 1048576;
  if (i < 2048){ biasL[i] = bih[i]+bhh[i]; return; } i -= 2048;
  if (i < 2048){ Wr[i] = Wih[i*531+512]; return; } i -= 2048;
  if (i < 36864){ int j=(int)(i>>11), n=(int)(i&2047);
    Wa[i] = Wih[n*531+513+j]; return; } i -= 36864;
  if (i < 524288){ headw1[i] = (bf16)(i<262144 ? aw1[i] : vw1[i-262144]); return; } i -= 524288;
  if (i < 1024){ headb1[i] = (i<512) ? ab1[i] : vb1[i-512]; return; } i -= 1024;
  if (i < 32768){ int n=(int)(i>>10), k=(int)(i&1023);
    float v = 0.f;
    if (n<18 && k<512) v = aw2[n*512+k];
    else if (n==18 && k>=512) v = vw2[k-512];
    w2cat[i] = (bf16)v; return; } i -= 32768;
  if (i < 32768){
    if (i < 16384){
      int row = (int)(i>>8), wd = (int)(i&255);
      uint32_t pk = pk2f(h0[row*512 + wd*2], h0[row*512 + wd*2 + 1]);
      hcurT[i] = pk & ~0x00010001u;
    } else {
      hcurT[i] = 0x00010000u;
    }
    return;
  }
}

// ---------------------------------------------------------------- conv1+conv2 fused
// 256 threads, 2 images/block, act1 in LDS at 80B pixel stride:
// 16B-aligned fragments (single ds_read_b128), banks spread via 8*ox+16*ky+20*kx.
__global__ __launch_bounds__(256,2) void k_conv12(
    const int* __restrict__ o, const bf16* __restrict__ w1b,
    const float* __restrict__ c1b, const bf16* __restrict__ w2r,
    const float* __restrict__ c2b, bf16* __restrict__ act2)
{
  __shared__ bf16 lact[2][16000];    // 2 img x 400 px x 80B (64000 B)
  const int tid = threadIdx.x;
  const int w = tid>>6, l = tid&63;
  const int img = w>>1, h = w&1;
  const long gimg = (long)blockIdx.x*2 + img;
  const int* ip = o + gimg*7056;
  char* lw = (char*)&lact[img][0];
  {
    bfrag bw[4];
    #pragma unroll
    for (int ks=0;ks<4;++ks) bw[ks] = ldg16(w1b + (l&31)*64 + ks*16 + 8*(l>>5));
    const float bias = c1b[l&31];
    for (int mt=h; mt<13; mt+=2){
      f32x16 acc = zero16();
      int m0 = mt*32 + (l&31);
      int p  = m0>399 ? 399 : m0;
      int oy = p/20, ox = p - oy*20;
      #pragma unroll
      for (int ks=0;ks<4;++ks){
        int ky = 2*ks + (l>>5);
        const int* q = ip + (oy*4+ky)*84 + ox*4;
        int4 i0 = *(const int4*)q;
        int4 i1 = *(const int4*)(q+4);
        bfrag a;
        a[0]=(bf16)(float)i0.x; a[1]=(bf16)(float)i0.y;
        a[2]=(bf16)(float)i0.z; a[3]=(bf16)(float)i0.w;
        a[4]=(bf16)(float)i1.x; a[5]=(bf16)(float)i1.y;
        a[6]=(bf16)(float)i1.z; a[7]=(bf16)(float)i1.w;
        acc = mfma32(a, bw[ks], acc);
      }
      #pragma unroll
      for (int r2=0;r2<16;++r2){
        int row = (r2&3) + 8*(r2>>2) + 4*(l>>5);
        int m = mt*32 + row;
        if (m < 400){
          float v = acc[r2] + bias; v = v>0.f ? v : 0.f;
          *(bf16*)(lw + m*80 + (l&31)*2) = (bf16)v;
        }
      }
    }
  }
  __syncthreads();
  {
    f32x16 acc2[3];
    #pragma unroll
    for (int a2=0;a2<3;++a2) acc2[a2]=zero16();
    int pb[3];
    #pragma unroll
    for (int mt=0;mt<3;++mt){
      int m = mt*32 + (l&31); int p = m>80 ? 80 : m;
      int oy = p/9, ox = p - oy*9;
      pb[mt] = (oy*2)*20 + ox*2;
    }
    #pragma unroll 4
    for (int ks=0; ks<32; ++ks){
      int k  = ks*16 + 8*(l>>5);
      int ky = k>>7, kx = (k>>5)&3, ci = k&31;
      bfrag b0 = ldg16(w2r + (32*h + (l&31))*512 + k);
      #pragma unroll
      for (int mt=0; mt<3; ++mt){
        int p2 = pb[mt] + ky*20 + kx;
        bfrag a = *(const bfrag*)(lw + p2*80 + ci*2);   // 16B aligned: ci in {0,8,16,24}
        acc2[mt] = mfma32(a, b0, acc2[mt]);
      }
    }
    const float bias2 = c2b[32*h + (l&31)];
    #pragma unroll
    for (int mt=0; mt<3; ++mt){
      #pragma unroll
      for (int r2=0;r2<16;++r2){
        int row = (r2&3) + 8*(r2>>2) + 4*(l>>5);
        int m = mt*32 + row;
        if (m < 81){
          float v = acc2[mt][r2] + bias2; v = v>0.f ? v : 0.f;
          act2[gimg*5184 + m*64 + 32*h + (l&31)] = (bf16)v;
        }
      }
    }
  }
}

// ---------------------------------------------------------------- conv3
__global__ __launch_bounds__(256,2) void k_conv3(
    const bf16* __restrict__ act2, const bf16* __restrict__ w3r,
    const float* __restrict__ c3b, bf16* __restrict__ act3)
{
  const int tid=threadIdx.x, w=tid>>6, l=tid&63;
  const long img = (long)blockIdx.x*4 + w;
  const bf16* A = act2 + img*5184;
  f32x16 acc[2][2];
  #pragma unroll
  for(int a2=0;a2<2;++a2){ acc[a2][0]=zero16(); acc[a2][1]=zero16(); }
  #pragma unroll 4
  for (int ks=0; ks<36; ++ks){
    int k  = ks*16 + 8*(l>>5);
    int ky = k/192, rem = k - ky*192, kx = rem>>6, ci = rem&63;
    bfrag b0 = ldg16(w3r + (l&31)*576 + k);
    bfrag b1 = ldg16(w3r + (32+(l&31))*576 + k);
    #pragma unroll
    for (int mt=0; mt<2; ++mt){
      int m = mt*32 + (l&31); int p = m>48 ? 48 : m;
      int oy = p/7, ox = p - oy*7;
      bfrag a = ldg16(A + ((oy+ky)*9 + (ox+kx))*64 + ci);
      acc[mt][0] = mfma32(a, b0, acc[mt][0]);
      acc[mt][1] = mfma32(a, b1, acc[mt][1]);
    }
  }
  const float bias0 = c3b[l&31], bias1 = c3b[32+(l&31)];
  #pragma unroll
  for (int mt=0; mt<2; ++mt){
    #pragma unroll
    for (int r2=0;r2<16;++r2){
      int row = (r2&3) + 8*(r2>>2) + 4*(l>>5);
      int m = mt*32 + row;
      if (m < 50){
        float v0 = 0.f, v1 = 0.f;
        if (m < 49){
          v0 = acc[mt][0][r2] + bias0; v0 = v0>0.f ? v0 : 0.f;
          v1 = acc[mt][1][r2] + bias1; v1 = v1>0.f ? v1 : 0.f;
        }
        act3[img*3200 + m*64 + (l&31)]      = (bf16)v0;
        act3[img*3200 + m*64 + 32 + (l&31)] = (bf16)v1;
      }
    }
  }
}

// ---------------------------------------------------------------- generic GEMM
template<bool RELU, bool OUTBF16>
__global__ __launch_bounds__(256,4) void k_gemm(
    const bf16* __restrict__ A, long lda,
    const bf16* __restrict__ W, long ldb,
    const float* __restrict__ bias,
    float* __restrict__ outF, bf16* __restrict__ outB, long ldo, int K,
    const float* __restrict__ fixR, const int* __restrict__ fixA,
    const float* __restrict__ fixWr, const float* __restrict__ fixWa)
{
  __shared__ bf16 sA[8192];
  char* sb = (char*)sA;
  const int tid=threadIdx.x, w=tid>>6, l=tid&63;
  const int m0 = blockIdx.x*64, n0 = blockIdx.y*128;
  f32x16 acc[2]; acc[0]=zero16(); acc[1]=zero16();
  const int mt = w&1;
  const int rowa = mt*32 + (l&31);
  for (int kc=0; kc<K; kc+=128){
    __syncthreads();
    #pragma unroll
    for (int j=0;j<4;++j){
      int idx = j*64 + l;
      int row = w*16 + (idx>>4);
      int seg = idx&15;
      const bf16* gp = A + (long)(m0+row)*lda + kc + (((seg*16) ^ ((row&15)<<4))>>1);
      gl_lds16(gp, sb + w*4096 + j*1024);
    }
    asm volatile("s_waitcnt vmcnt(0)" ::: "memory");
    __syncthreads();
    #pragma unroll
    for (int ks=0; ks<8; ++ks){
      bfrag a = *(const bfrag*)(sb + rowa*256 + ((ks*32 + (l>>5)*16) ^ ((rowa&15)<<4)));
      #pragma unroll
      for (int j=0;j<2;++j){
        int nt = (w>>1)*2 + j;
        bfrag b = ldg16(W + (long)(n0 + nt*32 + (l&31))*ldb + kc + ks*16 + 8*(l>>5));
        acc[j] = mfma32(a, b, acc[j]);
      }
    }
  }
  #pragma unroll
  for (int j=0;j<2;++j){
    int nt = (w>>1)*2 + j;
    int gc = n0 + nt*32 + (l&31);
    float bv = bias ? bias[gc] : 0.f;
    float wrv = fixR ? fixWr[gc] : 0.f;
    #pragma unroll
    for (int r2=0;r2<16;++r2){
      int row = (r2&3) + 8*(r2>>2) + 4*(l>>5);
      long gr = m0 + mt*32 + row;
      float v = acc[j][r2] + bv;
      if (fixR) v += fixR[gr]*wrv + fixWa[(long)fixA[gr]*2048 + gc];
      if (RELU) v = v>0.f ? v : 0.f;
      if (OUTBF16) outB[gr*ldo + gc] = (bf16)v;
      else         outF[gr*ldo + gc] = v;
    }
  }
}

// ---------------------------------------------------------------- LSTM recurrence (single 80-step dispatch)
// W_hh pinned in VGPRs; sc1 tag-in-data h exchange; G read as bf16.
__global__ __launch_bounds__(256,1) void k_lstm(
    const bf16* __restrict__ G, const int* __restrict__ done,
    const float* __restrict__ c0, const bf16* __restrict__ Whh,
    uint32_t* __restrict__ hcurT, bf16* __restrict__ hseq,
    float* __restrict__ outH, float* __restrict__ outC)
{
  __shared__ bf16 sh2[8192];         // 16 frags x 64 lanes x 8bf16 (16KB)
  __shared__ float sg[4][16][33];
  __shared__ float sc[16][33];
  __shared__ char  sdone[80][16];
  const int tid=threadIdx.x, w=tid>>6, l=tid&63;
  const int blk=blockIdx.x;
  const int grp=(blk&7)>>1, jj=((blk&1)<<3)|(blk>>3);
  const int bb = grp*16, uu = jj*32;

  for (int p=tid; p<512; p+=256){ int m=p>>5, u=p&31; sc[m][u] = c0[(bb+m)*512 + uu + u]; }
  for (int p=tid; p<1280; p+=256){ int t=p>>4, m=p&15; sdone[t][m] = (char)done[t*64 + bb + m]; }

  // W_hh fragments -> registers, pinned (cannot be rematerialized past the asm)
  bfrag wb0[16], wb1[16];
  {
    const long row0 = (long)w*512 + uu + (l&15);
    #pragma unroll
    for (int ks=0; ks<16; ++ks){
      int k = ks*32 + 8*(l>>4);
      wb0[ks] = ldg16(Whh + row0*512 + k);
      wb1[ks] = ldg16(Whh + (row0+16)*512 + k);
      asm volatile("" : "+v"(wb0[ks]), "+v"(wb1[ks]));
    }
  }

  char* shb = (char*)sh2;
  const int loff = l*16;
  const int srow  = tid>>4;
  const int sci   = tid&15;

  __syncthreads();

  for (int t=0; t<80; ++t){
    // (a) G loads for this step — independent of h, overlap the poll
    float gv0[4], gv1[4];
    {
      const bf16* Gt = G + ((long)t*64 + bb)*2048 + w*512 + uu;
      #pragma unroll
      for (int r2=0;r2<4;++r2){
        int m2 = (l>>4)*4 + r2;
        gv0[r2] = (float)Gt[(long)m2*2048 + (l&15)];
        gv1[r2] = (float)Gt[(long)m2*2048 + 16 + (l&15)];
      }
    }
    __builtin_amdgcn_sched_barrier(0);
    // (b) poll tagged bf16-pair h words for step t
    {
      const uint32_t* hb = hcurT + (size_t)(t&1)*16384 + (size_t)(bb+srow)*256 + sci*16;
      u32x4 hv[4];
      const uint32_t expPat = ((uint32_t)(t&1)) | (((uint32_t)((t>>1)&1))<<16);
      for (;;){
        #pragma unroll
        for (int j2=0;j2<4;++j2) hv[j2] = ldcg4(hb + j2*4);
        asm volatile("s_waitcnt vmcnt(0)" ::: "memory");
        bool ok = true;
        #pragma unroll
        for (int j2=0;j2<4;++j2){
          ok &= ((hv[j2][0]&0x00010001u)==expPat) & ((hv[j2][1]&0x00010001u)==expPat)
              & ((hv[j2][2]&0x00010001u)==expPat) & ((hv[j2][3]&0x00010001u)==expPat);
        }
        if (__all(ok)) break;
        __builtin_amdgcn_s_sleep(1);
      }
      if (sdone[t][srow]){
        #pragma unroll
        for (int j2=0;j2<4;++j2){ u32x4 z = {0,0,0,0}; hv[j2] = z; }
      } else {
        #pragma unroll
        for (int j2=0;j2<4;++j2){
          hv[j2][0] &= ~0x00010001u; hv[j2][1] &= ~0x00010001u;
          hv[j2][2] &= ~0x00010001u; hv[j2][3] &= ~0x00010001u;
        }
      }
      #pragma unroll
      for (int j=0;j<4;++j){
        *(u32x4*)(shb + sci*1024 + ((((srow + 16*j)*16)) ^ ((sci&7)<<4))) = hv[j];
      }
    }
    __syncthreads();
    // (c) h @ Whh^T  (A from LDS, B from pinned registers)
    f32x4 a0e = zero4(), a0o = zero4(), a1e = zero4(), a1o = zero4();
    #pragma unroll
    for (int ks=0; ks<16; ++ks){
      bfrag a = *(const bfrag*)(shb + ks*1024 + (loff ^ ((ks&7)<<4)));
      if (ks & 1){ a0o = mfma16(a, wb0[ks], a0o); a1o = mfma16(a, wb1[ks], a1o); }
      else       { a0e = mfma16(a, wb0[ks], a0e); a1e = mfma16(a, wb1[ks], a1e); }
    }
    #pragma unroll
    for (int r2=0;r2<4;++r2){
      int m = (l>>4)*4 + r2;
      sg[w][m][(l&15)]    = a0e[r2] + a0o[r2] + gv0[r2];
      sg[w][m][16+(l&15)] = a1e[r2] + a1o[r2] + gv1[r2];
    }
    __syncthreads();
    // (d) gates + cell + publish tagged h
    {
      int p0 = tid*2; int m = p0>>5, u = p0&31;
      int dn = sdone[t][m];
      float c_0 = dn ? 0.f : sc[m][u];
      float c_1 = dn ? 0.f : sc[m][u+1];
      float i0=sg[0][m][u],   f0=sg[1][m][u],   g0=sg[2][m][u],   o0=sg[3][m][u];
      float i1=sg[0][m][u+1], f1=sg[1][m][u+1], g1=sg[2][m][u+1], o1=sg[3][m][u+1];
      float cn0 = sigm(f0)*c_0 + sigm(i0)*ftanh(g0);
      float cn1 = sigm(f1)*c_1 + sigm(i1)*ftanh(g1);
      float h_0 = sigm(o0)*ftanh(cn0);
      float h_1 = sigm(o1)*ftanh(cn1);
      sc[m][u] = cn0; sc[m][u+1] = cn1;
      uint32_t pk = pk2f(h_0, h_1);
      int p1 = (t+1)&3;
      uint32_t pat = ((uint32_t)(p1&1)) | (((uint32_t)(p1>>1))<<16);
      uint32_t pkT = (pk & ~0x00010001u) | pat;
      __hip_atomic_store(
          hcurT + (size_t)((t+1)&1)*16384 + (size_t)(bb+m)*256 + ((uu+u)>>1),
          pkT, __ATOMIC_RELAXED, __HIP_MEMORY_SCOPE_AGENT);
      *(uint32_t*)(hseq + ((long)t*64 + bb + m)*512 + uu + u) = pk;
      if (t == 79){
        outH[(bb+m)*512 + uu + u]   = h_0;  outH[(bb+m)*512 + uu + u+1] = h_1;
        outC[(bb+m)*512 + uu + u]   = cn0;  outC[(bb+m)*512 + uu + u+1] = cn1;
      }
    }
  }
}

// ---------------------------------------------------------------- fused head2 + dueling combine
__global__ __launch_bounds__(256) void k_qhead(
    const bf16* __restrict__ zav, const bf16* __restrict__ w2cat,
    const float* __restrict__ ab2, const float* __restrict__ vb2,
    float* __restrict__ q)
{
  __shared__ float sq[4][16][33];
  const int tid=threadIdx.x, w=tid>>6, l=tid&63;
  const int s0 = blockIdx.x*64 + w*16;
  f32x4 acc0 = zero4(), acc1 = zero4();
  const int row = l&15;
  #pragma unroll 4
  for (int ks=0; ks<32; ++ks){
    int k = ks*32 + 8*(l>>4);
    bfrag a  = ldg16(zav + (long)(s0+row)*1024 + k);
    bfrag b0 = ldg16(w2cat + (l&15)*1024 + k);
    bfrag b1 = ldg16(w2cat + (16+(l&15))*1024 + k);
    acc0 = mfma16(a, b0, acc0);
    acc1 = mfma16(a, b1, acc1);
  }
  #pragma unroll
  for (int r2=0;r2<4;++r2){
    int m = (l>>4)*4 + r2;
    sq[w][m][l&15]      = acc0[r2];
    sq[w][m][16+(l&15)] = acc1[r2];
  }
  __syncthreads();
  if (l < 16){
    int s = s0 + l;
    float av[18]; float sum = 0.f;
    #pragma unroll
    for (int j=0;j<18;++j){ av[j] = sq[w][l][j] + ab2[j]; sum += av[j]; }
    float val = sq[w][l][18] + vb2[0];
    float mean = sum * (1.f/18.f);
    #pragma unroll
    for (int j=0;j<18;++j) q[(long)s*18 + j] = val + av[j] - mean;
  }
}

// ================================================================ host
extern "C" void kernel_launch(void* const* d_in, const int* in_sizes, int n_in,
                              void* d_out, int out_size, void* d_ws, size_t ws_size,
                              hipStream_t stream)
{
  (void)in_sizes; (void)n_in; (void)out_size;
  const int*   o_in = (const int*)  d_in[0];
  const int*   a_in = (const int*)  d_in[1];
  const float* r_in = (const float*)d_in[2];
  const int*   done = (const int*)  d_in[3];
  const float* h0   = (const float*)d_in[4];
  const float* c0   = (const float*)d_in[5];
  const float* c1w  = (const float*)d_in[6],  *c1b=(const float*)d_in[7];
  const float* c2w  = (const float*)d_in[8],  *c2b=(const float*)d_in[9];
  const float* c3w  = (const float*)d_in[10], *c3b=(const float*)d_in[11];
  const float* fcw  = (const float*)d_in[12], *fcb=(const float*)d_in[13];
  const float* Wih  = (const float*)d_in[14], *WhhF=(const float*)d_in[15];
  const float* bih  = (const float*)d_in[16], *bhh=(const float*)d_in[17];
  const float* aw1  = (const float*)d_in[18], *ab1=(const float*)d_in[19];
  const float* aw2  = (const float*)d_in[20], *ab2=(const float*)d_in[21];
  const float* vw1  = (const float*)d_in[22], *vb1=(const float*)d_in[23];
  const float* vw2  = (const float*)d_in[24], *vb2=(const float*)d_in[25];

  char* ws = (char*)d_ws;
  size_t off = 0;
  auto alloc = [&](size_t b){ size_t p = off; off = (off + b + 255) & ~(size_t)255; return p; };
  bf16*  act2   = (bf16*) (ws + alloc(53084160));   // 5120 x 5184   (G aliases later)
  bf16*  act3   = (bf16*) (ws + alloc(32768000));   // 5120 x 3200   (zav aliases later)
  bf16*  hidden = (bf16*) (ws + alloc(5242880));    // 5120 x 512    (hseq aliases later)
  uint32_t* hcurT = (uint32_t*)(ws + alloc(131072));// 2 x 64 x 256 tagged bf16-pairs
  bf16*  w1b    = (bf16*) (ws + alloc(4096));
  bf16*  w2r    = (bf16*) (ws + alloc(65536));
  bf16*  w3r    = (bf16*) (ws + alloc(73728));
  bf16*  fcwr   = (bf16*) (ws + alloc(3276800));
  bf16*  Wx     = (bf16*) (ws + alloc(2097152));
  bf16*  Whh    = (bf16*) (ws + alloc(2097152));
  float* biasL  = (float*)(ws + alloc(8192));
  float* Wr     = (float*)(ws + alloc(8192));
  float* Wa     = (float*)(ws + alloc(147456));
  bf16*  headw1 = (bf16*) (ws + alloc(1048576));
  float* headb1 = (float*)(ws + alloc(4096));
  bf16*  w2cat  = (bf16*) (ws + alloc(65536));
  if (off > ws_size) return;

  bf16*  G    = act2;            // 21MB <= 53.1MB (bf16 gates)
  bf16*  hseq = hidden;
  bf16*  zav  = act3;            // 10.5MB <= 32.8MB

  float* qout = (float*)d_out;
  float* outH = qout + 92160;
  float* outC = qout + 124928;

  k_prep<<<17340, 256, 0, stream>>>(c1w, c2w, c3w, fcw, Wih, WhhF, bih, bhh,
      aw1, aw2, vw1, vw2, h0, ab1, vb1, w1b, w2r, w3r, fcwr, Wx, Whh,
      biasL, Wr, Wa, headw1, headb1, w2cat, hcurT);

  k_conv12<<<2560, 256, 0, stream>>>(o_in, w1b, c1b, w2r, c2b, act2);
  k_conv3<<<1280, 256, 0, stream>>>(act2, w3r, c3b, act3);
  k_gemm<true,true><<<dim3(80,4), 256, 0, stream>>>(
      act3, 3200, fcwr, 3200, fcb, nullptr, hidden, 512, 3200,
      nullptr, nullptr, nullptr, nullptr);
  // G = hidden @ Wx^T + bias + r*Wr + Wa[a]  -> bf16
  k_gemm<false,true><<<dim3(80,16), 256, 0, stream>>>(
      hidden, 512, Wx, 512, biasL, nullptr, G, 2048, 512,
      r_in, a_in, Wr, Wa);

  k_lstm<<<64, 256, 0, stream>>>(G, done, c0, Whh, hcurT, hseq, outH, outC);

  k_gemm<true,true><<<dim3(80,8), 256, 0, stream>>>(
      hseq, 512, headw1, 512, headb1, nullptr, zav, 1024, 512,
      nullptr, nullptr, nullptr, nullptr);
  k_qhead<<<80, 256, 0, stream>>>(zav, w2cat, ab2, vb2, qout);
}